// Round 1
// baseline (1222.818 us; speedup 1.0000x reference)
//
#include <hip/hip_runtime.h>
#include <cstdint>

#define BATCH   2
#define NANCH   261888
#define PRE_NMS 6000
#define PROP    1000
#define NBUCK   65536
#define CAND_CAP 8192
#define SORTN   8192
#define NTILES  94          // ceil(6000/64)
#define NMS_THR 0.7f

typedef unsigned long long u64;
typedef unsigned int u32;

// ---- workspace layout (bytes) ----
#define HIST_OFF   0u
#define HIST_BYTES (BATCH*NBUCK*4)              // 524288
#define META_OFF   (HIST_OFF + HIST_BYTES)
#define META_BYTES 256
#define CAND_OFF   (META_OFF + META_BYTES)      // 8-byte aligned
#define CAND_BYTES (BATCH*CAND_CAP*8)           // 131072
#define BOXES_OFF  (CAND_OFF + CAND_BYTES)      // 16-byte aligned
#define BOXES_BYTES (BATCH*PRE_NMS*16)          // 192000
#define REM_OFF    (BOXES_OFF + BOXES_BYTES)
#define REM_BYTES  (BATCH*6016)
#define KEEP_OFF   (REM_OFF + REM_BYTES)
#define KEEP_BYTES (BATCH*6016)
#define MASK_OFF   (KEEP_OFF + KEEP_BYTES)      // 8-byte aligned

__global__ void k_zero(u32* p, int n) {
    int i = blockIdx.x * blockDim.x + threadIdx.x;
    if (i < n) p[i] = 0u;
}

// bucket by score value (monotonic); scores are uniform in [0,1)
__device__ __forceinline__ int score_bucket(float s) {
    int bk = (int)(s * 65536.0f);
    return bk < 0 ? 0 : (bk > 65535 ? 65535 : bk);
}

__global__ void k_hist(const float* __restrict__ cls, int* __restrict__ hist) {
    int b = blockIdx.y;
    int stride = gridDim.x * blockDim.x;
    for (int i = blockIdx.x * blockDim.x + threadIdx.x; i < NANCH; i += stride) {
        float s = cls[((size_t)b * NANCH + i) * 2 + 1];
        atomicAdd(&hist[b * NBUCK + score_bucket(s)], 1);
    }
}

// find largest bucket T with count(bucket >= T) >= PRE_NMS; also zero cand counts
__global__ void k_thresh(const int* __restrict__ hist, int* __restrict__ meta) {
    __shared__ int chunk[256];
    __shared__ int suffix[256];
    int b = blockIdx.x, t = threadIdx.x;
    const int* h = hist + b * NBUCK;
    int s = 0;
    for (int c = 0; c < 256; ++c) s += h[t * 256 + c];
    chunk[t] = s;
    __syncthreads();
    if (t == 0) {
        int run = 0;
        for (int u = 255; u >= 0; --u) { suffix[u] = run; run += chunk[u]; }
        meta[BATCH + b] = 0;   // candidate count
    }
    __syncthreads();
    if (suffix[t] < PRE_NMS && suffix[t] + chunk[t] >= PRE_NMS) {
        int running = suffix[t];
        for (int c = 255; c >= 0; --c) {
            running += h[t * 256 + c];
            if (running >= PRE_NMS) { meta[b] = t * 256 + c; break; }
        }
    }
}

__global__ void k_compact(const float* __restrict__ cls, const int* __restrict__ meta,
                          int* __restrict__ cnt, u64* __restrict__ cand) {
    int b = blockIdx.y;
    int thr = meta[b];
    int stride = gridDim.x * blockDim.x;
    for (int i = blockIdx.x * blockDim.x + threadIdx.x; i < NANCH; i += stride) {
        float s = cls[((size_t)b * NANCH + i) * 2 + 1];
        if (score_bucket(s) >= thr) {
            int pos = atomicAdd(&cnt[b], 1);
            if (pos < CAND_CAP) {
                u32 sb = __float_as_uint(s);
                cand[b * CAND_CAP + pos] = ((u64)sb << 32) | (u32)(~(u32)i);
            }
        }
    }
}

// per-batch: bitonic sort 8192 keys descending in LDS, then decode top-6000 boxes
__global__ __launch_bounds__(1024) void k_sortbuild(
        const u64* __restrict__ cand, const int* __restrict__ cnt_p,
        const float4* __restrict__ anchors, const float4* __restrict__ bbox,
        float4* __restrict__ boxes) {
    #pragma clang fp contract(off)
    __shared__ u64 sk[SORTN];
    int b = blockIdx.x, t = threadIdx.x;
    int cnt = cnt_p[b]; if (cnt > CAND_CAP) cnt = CAND_CAP;
    for (int i = t; i < SORTN; i += 1024)
        sk[i] = (i < cnt) ? cand[b * CAND_CAP + i] : 0ull;
    __syncthreads();
    for (int k = 2; k <= SORTN; k <<= 1) {
        for (int j = k >> 1; j > 0; j >>= 1) {
            for (int i = t; i < SORTN; i += 1024) {
                int l = i ^ j;
                if (l > i) {
                    u64 a = sk[i], c = sk[l];
                    bool up = ((i & k) == 0);
                    if (up ? (a < c) : (a > c)) { sk[i] = c; sk[l] = a; }
                }
            }
            __syncthreads();
        }
    }
    for (int r = t; r < PRE_NMS; r += 1024) {
        u64 key = sk[r];
        u32 idx = ~(u32)(key & 0xffffffffull);
        float4 a = anchors[(size_t)b * NANCH + idx];
        float4 d = bbox[(size_t)b * NANCH + idx];
        float dy = d.x * 0.1f, dx = d.y * 0.1f, dh = d.z * 0.2f, dw = d.w * 0.2f;
        float h = a.z - a.x;
        float w = a.w - a.y;
        float cy = a.x + 0.5f * h + dy * h;
        float cx = a.y + 0.5f * w + dx * w;
        h = h * expf(dh);
        w = w * expf(dw);
        float y1 = cy - 0.5f * h;
        float x1 = cx - 0.5f * w;
        float y2 = y1 + h;
        float x2 = x1 + w;
        y1 = fminf(fmaxf(y1, 0.f), 1.f);
        x1 = fminf(fmaxf(x1, 0.f), 1.f);
        y2 = fminf(fmaxf(y2, 0.f), 1.f);
        x2 = fminf(fmaxf(x2, 0.f), 1.f);
        boxes[b * PRE_NMS + r] = make_float4(y1, x1, y2, x2);
    }
}

// mask[(b*6000+j)*Cstride + tIdx] : bit l = IoU(box_j, box_{64*(T0+tIdx)+l}) > 0.7
__global__ void k_mask(const float4* __restrict__ boxes, u64* __restrict__ mask,
                       int T0, int Cstride) {
    #pragma clang fp contract(off)
    __shared__ float4 tb[64];
    __shared__ float ta[64];
    int b = blockIdx.z;
    int tIdx = blockIdx.y;
    int T = T0 + tIdx;
    int t = threadIdx.x;
    if (t < 64) {
        int i = T * 64 + t;
        float4 v = (i < PRE_NMS) ? boxes[b * PRE_NMS + i] : make_float4(0.f, 0.f, 0.f, 0.f);
        tb[t] = v;
        ta[t] = (v.z - v.x) * (v.w - v.y);
    }
    __syncthreads();
    int j = blockIdx.x * blockDim.x + t;
    if (j < PRE_NMS) {
        float4 bj = boxes[b * PRE_NMS + j];
        float areaj = (bj.z - bj.x) * (bj.w - bj.y);
        u64 wbits = 0;
        for (int l = 0; l < 64; ++l) {
            float4 bi = tb[l];
            float ih = fminf(bi.z, bj.z) - fmaxf(bi.x, bj.x); ih = fmaxf(ih, 0.f);
            float iw = fminf(bi.w, bj.w) - fmaxf(bi.y, bj.y); iw = fmaxf(iw, 0.f);
            float inter = ih * iw;
            float iou = inter / (ta[l] + areaj - inter + 1e-8f);
            if (iou > NMS_THR) wbits |= (1ull << l);
        }
        mask[((size_t)b * PRE_NMS + j) * Cstride + tIdx] = wbits;
    }
}

// serial greedy scan over tiles; one block per batch
__global__ __launch_bounds__(1024) void k_nms_scan(
        const u64* __restrict__ mask, unsigned char* __restrict__ removed,
        unsigned char* __restrict__ keep, int T0, int Ccount, int Cstride) {
    __shared__ u64 km;
    int b = blockIdx.x;
    unsigned char* rem = removed + b * 6016;
    unsigned char* kp  = keep + b * 6016;
    for (int tIdx = 0; tIdx < Ccount; ++tIdx) {
        int T = T0 + tIdx;
        int base = T * 64;
        int limit = PRE_NMS - base; if (limit > 64) limit = 64;
        if (threadIdx.x < 64) {
            int l = threadIdx.x;
            bool rm = (l < limit) ? (rem[base + l] != 0) : true;
            u64 m = (l < limit) ? mask[((size_t)b * PRE_NMS + base + l) * Cstride + tIdx] : 0ull;
            u64 rem64 = __ballot(rm);
            u64 keptmask = 0;
            for (int l0 = 0; l0 < limit; ++l0) {
                if (!((rem64 >> l0) & 1ull)) {       // uniform branch (rem64 replicated)
                    keptmask |= (1ull << l0);
                    rem64 |= __shfl(m, l0);
                }
            }
            if (l < limit) {
                kp[base + l]  = (unsigned char)((keptmask >> l) & 1ull);
                rem[base + l] = (unsigned char)((rem64 >> l) & 1ull);
            }
            if (l == 0) km = keptmask;
        }
        __syncthreads();
        u64 keptmask = km;
        if (keptmask) {
            for (int j = base + 64 + (int)threadIdx.x; j < PRE_NMS; j += 1024) {
                if (!rem[j]) {
                    u64 wd = mask[((size_t)b * PRE_NMS + j) * Cstride + tIdx];
                    if (wd & keptmask) rem[j] = 1;
                }
            }
        }
        __syncthreads();
    }
}

__global__ __launch_bounds__(1024) void k_output(
        const float4* __restrict__ boxes, const unsigned char* __restrict__ keep,
        float* __restrict__ out) {
    __shared__ int psum[1024];
    int b = blockIdx.x, t = threadIdx.x;
    for (int i = t; i < PROP * 4; i += 1024) out[b * PROP * 4 + i] = 0.f;
    const unsigned char* kp = keep + b * 6016;
    int j0 = t * 6;
    int cnt = 0;
    for (int u = 0; u < 6; ++u) { int j = j0 + u; if (j < PRE_NMS) cnt += kp[j]; }
    psum[t] = cnt;
    __syncthreads();
    for (int off = 1; off < 1024; off <<= 1) {
        int v = (t >= off) ? psum[t - off] : 0;
        __syncthreads();
        psum[t] += v;
        __syncthreads();
    }
    int rank = psum[t] - cnt;   // exclusive prefix
    float4* out4 = (float4*)(out + b * PROP * 4);
    for (int u = 0; u < 6; ++u) {
        int j = j0 + u;
        if (j < PRE_NMS && kp[j]) {
            if (rank < PROP) out4[rank] = boxes[b * PRE_NMS + j];
            rank++;
        }
    }
}

extern "C" void kernel_launch(void* const* d_in, const int* in_sizes, int n_in,
                              void* d_out, int out_size, void* d_ws, size_t ws_size,
                              hipStream_t stream) {
    const float*  cls     = (const float*)d_in[0];
    const float4* bbox    = (const float4*)d_in[1];
    const float4* anchors = (const float4*)d_in[2];
    float* out = (float*)d_out;
    char* w = (char*)d_ws;
    int*  hist    = (int*)(w + HIST_OFF);
    int*  meta    = (int*)(w + META_OFF);      // [0..1]=thr bucket, [2..3]=cand count
    u64*  cand    = (u64*)(w + CAND_OFF);
    float4* boxes = (float4*)(w + BOXES_OFF);
    unsigned char* removed = (unsigned char*)(w + REM_OFF);
    unsigned char* keep    = (unsigned char*)(w + KEEP_OFF);
    u64*  mask    = (u64*)(w + MASK_OFF);

    // adaptive mask chunk width so we fit in ws_size (constant across calls -> capture-safe)
    int C = NTILES;
    while (C > 1 && MASK_OFF + (size_t)BATCH * PRE_NMS * 8 * C > ws_size) C = (C + 1) / 2;

    k_zero<<<dim3((BATCH * NBUCK + 255) / 256), 256, 0, stream>>>((u32*)hist, BATCH * NBUCK);
    k_zero<<<dim3((REM_BYTES / 4 + 255) / 256), 256, 0, stream>>>((u32*)removed, REM_BYTES / 4);
    k_hist<<<dim3(256, BATCH), 256, 0, stream>>>(cls, hist);
    k_thresh<<<dim3(BATCH), 256, 0, stream>>>(hist, meta);
    k_compact<<<dim3(256, BATCH), 256, 0, stream>>>(cls, meta, meta + BATCH, cand);
    k_sortbuild<<<dim3(BATCH), 1024, 0, stream>>>(cand, meta + BATCH, anchors, bbox, boxes);
    for (int T0 = 0; T0 < NTILES; T0 += C) {
        int Cc = NTILES - T0; if (Cc > C) Cc = C;
        k_mask<<<dim3((PRE_NMS + 255) / 256, Cc, BATCH), 256, 0, stream>>>(boxes, mask, T0, C);
        k_nms_scan<<<dim3(BATCH), 1024, 0, stream>>>(mask, removed, keep, T0, Cc, C);
    }
    k_output<<<dim3(BATCH), 1024, 0, stream>>>(boxes, keep, out);
}

// Round 2
// 515.864 us; speedup vs baseline: 2.3704x; 2.3704x over previous
//
#include <hip/hip_runtime.h>
#include <cstdint>

#define BATCH   2
#define NANCH   261888
#define PRE_NMS 6000
#define PROP    1000
#define NBUCK   65536
#define CAND_CAP 8192
#define SORTN   8192
#define NT      94          // ceil(6000/64)
#define NMS_THR 0.7f

typedef unsigned long long u64;
typedef unsigned int u32;

// ---- workspace layout (bytes) ----
// live ranges: hist/cand die before k_mask writes mask -> overlap them with mask.
#define META_OFF   0u
#define BOXES_OFF  256u                          // 2*6000*16 = 192000
#define KEPTW_OFF  192512u                       // 2*96*8 = 1536
#define NZ_OFF     194048u                       // 2*94*2*8 = 3008
#define MASK_OFF   197120u                       // 2*94*94*64*8 = 9048064 -> end 9245184
#define HIST_OFF   197120u                       // overlaps mask (dead by then), 512KB
#define CAND_OFF   721408u                       // overlaps mask, 128KB -> end 852480

__global__ void k_zero(u32* p, int n) {
    int i = blockIdx.x * blockDim.x + threadIdx.x;
    if (i < n) p[i] = 0u;
}

__device__ __forceinline__ int score_bucket(float s) {
    int bk = (int)(s * 65536.0f);
    return bk < 0 ? 0 : (bk > 65535 ? 65535 : bk);
}

__global__ void k_hist(const float* __restrict__ cls, int* __restrict__ hist) {
    int b = blockIdx.y;
    int stride = gridDim.x * blockDim.x;
    for (int i = blockIdx.x * blockDim.x + threadIdx.x; i < NANCH; i += stride) {
        float s = cls[((size_t)b * NANCH + i) * 2 + 1];
        atomicAdd(&hist[b * NBUCK + score_bucket(s)], 1);
    }
}

__global__ void k_thresh(const int* __restrict__ hist, int* __restrict__ meta) {
    __shared__ int chunk[256];
    __shared__ int suffix[256];
    int b = blockIdx.x, t = threadIdx.x;
    const int* h = hist + b * NBUCK;
    int s = 0;
    for (int c = 0; c < 256; ++c) s += h[t * 256 + c];
    chunk[t] = s;
    __syncthreads();
    if (t == 0) {
        int run = 0;
        for (int u = 255; u >= 0; --u) { suffix[u] = run; run += chunk[u]; }
        meta[BATCH + b] = 0;   // candidate count
    }
    __syncthreads();
    if (suffix[t] < PRE_NMS && suffix[t] + chunk[t] >= PRE_NMS) {
        int running = suffix[t];
        for (int c = 255; c >= 0; --c) {
            running += h[t * 256 + c];
            if (running >= PRE_NMS) { meta[b] = t * 256 + c; break; }
        }
    }
}

__global__ void k_compact(const float* __restrict__ cls, const int* __restrict__ meta,
                          int* __restrict__ cnt, u64* __restrict__ cand) {
    int b = blockIdx.y;
    int thr = meta[b];
    int stride = gridDim.x * blockDim.x;
    for (int i = blockIdx.x * blockDim.x + threadIdx.x; i < NANCH; i += stride) {
        float s = cls[((size_t)b * NANCH + i) * 2 + 1];
        if (score_bucket(s) >= thr) {
            int pos = atomicAdd(&cnt[b], 1);
            if (pos < CAND_CAP) {
                u32 sb = __float_as_uint(s);
                cand[b * CAND_CAP + pos] = ((u64)sb << 32) | (u32)(~(u32)i);
            }
        }
    }
}

// per-batch: bitonic sort 8192 keys descending in LDS, then decode top-6000 boxes
__global__ __launch_bounds__(1024) void k_sortbuild(
        const u64* __restrict__ cand, const int* __restrict__ cnt_p,
        const float4* __restrict__ anchors, const float4* __restrict__ bbox,
        float4* __restrict__ boxes) {
    #pragma clang fp contract(off)
    __shared__ u64 sk[SORTN];
    int b = blockIdx.x, t = threadIdx.x;
    int cnt = cnt_p[b]; if (cnt > CAND_CAP) cnt = CAND_CAP;
    for (int i = t; i < SORTN; i += 1024)
        sk[i] = (i < cnt) ? cand[b * CAND_CAP + i] : 0ull;
    __syncthreads();
    for (int k = 2; k <= SORTN; k <<= 1) {
        for (int j = k >> 1; j > 0; j >>= 1) {
            for (int i = t; i < SORTN; i += 1024) {
                int l = i ^ j;
                if (l > i) {
                    u64 a = sk[i], c = sk[l];
                    bool up = ((i & k) == 0);
                    if (up ? (a < c) : (a > c)) { sk[i] = c; sk[l] = a; }
                }
            }
            __syncthreads();
        }
    }
    for (int r = t; r < PRE_NMS; r += 1024) {
        u64 key = sk[r];
        u32 idx = ~(u32)(key & 0xffffffffull);
        float4 a = anchors[(size_t)b * NANCH + idx];
        float4 d = bbox[(size_t)b * NANCH + idx];
        float dy = d.x * 0.1f, dx = d.y * 0.1f, dh = d.z * 0.2f, dw = d.w * 0.2f;
        float h = a.z - a.x;
        float w = a.w - a.y;
        float cy = a.x + 0.5f * h + dy * h;
        float cx = a.y + 0.5f * w + dx * w;
        h = h * expf(dh);
        w = w * expf(dw);
        float y1 = cy - 0.5f * h;
        float x1 = cx - 0.5f * w;
        float y2 = y1 + h;
        float x2 = x1 + w;
        y1 = fminf(fmaxf(y1, 0.f), 1.f);
        x1 = fminf(fmaxf(x1, 0.f), 1.f);
        y2 = fminf(fmaxf(y2, 0.f), 1.f);
        x2 = fminf(fmaxf(x2, 0.f), 1.f);
        boxes[b * PRE_NMS + r] = make_float4(y1, x1, y2, x2);
    }
}

// block-tiled mask: mask[((b*NT+T)*NT+W)*64 + lane], bit c = IoU(row box 64W+lane, col box 64T+c) > thr
// nz[(b*NT+T)*2 + (W>>6)] bit (W&63): any suppression bit in block (T, W), W > T only.
__global__ __launch_bounds__(256) void k_mask(const float4* __restrict__ boxes,
                                              u64* __restrict__ mask, u64* __restrict__ nz) {
    #pragma clang fp contract(off)
    __shared__ float4 tb[64];
    __shared__ float ta[64];
    int b = blockIdx.z;
    int T = blockIdx.y;
    int w = threadIdx.x >> 6, lane = threadIdx.x & 63;
    int W = blockIdx.x * 4 + w;
    if (threadIdx.x < 64) {
        int c = T * 64 + threadIdx.x;
        float4 v = (c < PRE_NMS) ? boxes[b * PRE_NMS + c] : make_float4(0.f, 0.f, 0.f, 0.f);
        tb[threadIdx.x] = v;
        ta[threadIdx.x] = (v.z - v.x) * (v.w - v.y);
    }
    __syncthreads();
    if (W < T || W >= NT) return;
    int j = W * 64 + lane;
    u64 word = 0;
    if (j < PRE_NMS) {
        float4 bj = boxes[b * PRE_NMS + j];
        float areaj = (bj.z - bj.x) * (bj.w - bj.y);
        for (int c = 0; c < 64; ++c) {
            float4 bi = tb[c];
            float ih = fminf(bi.z, bj.z) - fmaxf(bi.x, bj.x); ih = fmaxf(ih, 0.f);
            float iw = fminf(bi.w, bj.w) - fmaxf(bi.y, bj.y); iw = fmaxf(iw, 0.f);
            float inter = ih * iw;
            float iou = inter / (ta[c] + areaj - inter + 1e-8f);
            if (iou > NMS_THR) word |= (1ull << c);
        }
    }
    mask[(((size_t)b * NT + T) * NT + W) * 64 + lane] = word;
    if (W > T) {
        u64 any = __ballot(word != 0);
        if (lane == 0 && any)
            atomicOr((unsigned long long*)&nz[(b * NT + T) * 2 + (W >> 6)], 1ull << (W & 63));
    }
}

// single wave per batch; removed bitmask in LDS; sparse serial resolve + nz-driven propagate
__global__ __launch_bounds__(64) void k_scan(const u64* __restrict__ mask,
                                             const u64* __restrict__ nz,
                                             u64* __restrict__ keptw) {
    __shared__ u64 remAll[NT];
    int b = blockIdx.x, lane = threadIdx.x;
    for (int i = lane; i < NT; i += 64) remAll[i] = 0;
    __syncthreads();
    u64 himaskL = (lane == 63) ? 0ull : (~0ull << (lane + 1));
    size_t basebt = (size_t)b * NT;
    u64 m = mask[((basebt + 0) * NT + 0) * 64 + lane];
    for (int T = 0; T < NT; ++T) {
        u64 m_next = (T + 1 < NT) ? mask[((basebt + T + 1) * NT + (T + 1)) * 64 + lane] : 0ull;
        int limit = PRE_NMS - T * 64; if (limit > 64) limit = 64;
        u64 valid = (limit >= 64) ? ~0ull : ((1ull << limit) - 1ull);
        u64 rem = remAll[T];
        u64 pending = valid & ~rem;
        u64 ib = __ballot((m & himaskL) != 0ull);
        u64 todo = pending & ib;
        while (todo) {
            int l0 = __ffsll((unsigned long long)todo) - 1;
            todo &= todo - 1;
            if ((rem >> l0) & 1ull) continue;
            u64 sup = __shfl(m, l0);
            sup &= (l0 == 63) ? 0ull : (~0ull << (l0 + 1));
            rem |= sup;
            todo &= ~sup;
        }
        u64 kept = valid & ~rem;
        if (lane == 0) keptw[b * 96 + T] = kept;
        // propagate to nonzero future blocks only
        u64 nz0 = nz[(basebt + T) * 2 + 0];
        u64 nz1 = nz[(basebt + T) * 2 + 1];
        if (T < 64) {
            nz0 &= (T == 63) ? 0ull : (~0ull << (T + 1));
        } else {
            nz0 = 0ull;
            nz1 &= (~0ull << (T - 63));
        }
        bool updated = false;
        while (nz0 | nz1) {
            int W;
            if (nz0) { W = __ffsll((unsigned long long)nz0) - 1; nz0 &= nz0 - 1; }
            else     { W = 64 + __ffsll((unsigned long long)nz1) - 1; nz1 &= nz1 - 1; }
            u64 mw = mask[((basebt + T) * NT + W) * 64 + lane];
            u64 ra = __ballot((mw & kept) != 0ull);
            if (ra) { if (lane == 0) remAll[W] |= ra; updated = true; }
        }
        if (updated) __syncthreads();
        m = m_next;
    }
}

__global__ __launch_bounds__(1024) void k_output(
        const float4* __restrict__ boxes, const u64* __restrict__ keptw,
        float* __restrict__ out) {
    __shared__ int wp[NT + 1];
    int b = blockIdx.x, t = threadIdx.x;
    for (int i = t; i < PROP * 4; i += 1024) out[b * PROP * 4 + i] = 0.f;
    if (t < NT) wp[t + 1] = __popcll(keptw[b * 96 + t]);
    if (t == 0) wp[0] = 0;
    __syncthreads();
    if (t == 0) { for (int i = 1; i <= NT; ++i) wp[i] += wp[i - 1]; }
    __syncthreads();
    float4* out4 = (float4*)(out + b * PROP * 4);
    for (int j = t; j < PRE_NMS; j += 1024) {
        u64 w = keptw[b * 96 + (j >> 6)];
        int bit = j & 63;
        if ((w >> bit) & 1ull) {
            int rank = wp[j >> 6] + __popcll(w & ((1ull << bit) - 1ull));
            if (rank < PROP) out4[rank] = boxes[b * PRE_NMS + j];
        }
    }
}

extern "C" void kernel_launch(void* const* d_in, const int* in_sizes, int n_in,
                              void* d_out, int out_size, void* d_ws, size_t ws_size,
                              hipStream_t stream) {
    const float*  cls     = (const float*)d_in[0];
    const float4* bbox    = (const float4*)d_in[1];
    const float4* anchors = (const float4*)d_in[2];
    float* out = (float*)d_out;
    char* w = (char*)d_ws;
    int*    meta  = (int*)(w + META_OFF);      // [0..1]=thr bucket, [2..3]=cand count
    float4* boxes = (float4*)(w + BOXES_OFF);
    u64*    keptw = (u64*)(w + KEPTW_OFF);
    u64*    nz    = (u64*)(w + NZ_OFF);
    u64*    mask  = (u64*)(w + MASK_OFF);
    int*    hist  = (int*)(w + HIST_OFF);      // overlaps mask (dead before k_mask)
    u64*    cand  = (u64*)(w + CAND_OFF);      // overlaps mask (dead before k_mask)

    k_zero<<<dim3((BATCH * NBUCK + 255) / 256), 256, 0, stream>>>((u32*)hist, BATCH * NBUCK);
    k_zero<<<dim3(((1536 + 3008) / 4 + 255) / 256), 256, 0, stream>>>((u32*)keptw, (1536 + 3008) / 4);
    k_hist<<<dim3(256, BATCH), 256, 0, stream>>>(cls, hist);
    k_thresh<<<dim3(BATCH), 256, 0, stream>>>(hist, meta);
    k_compact<<<dim3(256, BATCH), 256, 0, stream>>>(cls, meta, meta + BATCH, cand);
    k_sortbuild<<<dim3(BATCH), 1024, 0, stream>>>(cand, meta + BATCH, anchors, bbox, boxes);
    k_mask<<<dim3(24, NT, BATCH), 256, 0, stream>>>(boxes, mask, nz);
    k_scan<<<dim3(BATCH), 64, 0, stream>>>(mask, nz, keptw);
    k_output<<<dim3(BATCH), 1024, 0, stream>>>(boxes, keptw, out);
}

// Round 3
// 341.927 us; speedup vs baseline: 3.5763x; 1.5087x over previous
//
#include <hip/hip_runtime.h>
#include <cstdint>

#define BATCH   2
#define NANCH   261888
#define PRE_NMS 6000
#define PROP    1000
#define NBUCK   65536
#define SEG_CAP 8192
#define NT      94          // ceil(6000/64)
#define NMS_THR 0.7f

typedef unsigned long long u64;
typedef unsigned int u32;

// ---- workspace layout (bytes) ----
// boxes/keptw/nz live across the whole pipeline; all top-k scratch is dead
// before k_mask writes the mask region, so it overlaps MASK_OFF.
#define META_OFF   0u
#define BOXES_OFF  256u                          // 2*6000*16 = 192000
#define KEPTW_OFF  192512u                       // 2*96*8  = 1536
#define NZ_OFF     194048u                       // 2*94*2*8 = 3008
#define MASK_OFF   197120u                       // 2*94*94*64*8 = 9048064 -> end 9245184
// overlapped scratch (dead before k_mask):
#define HIST_OFF   197120u                       // 2*64K*4 = 512KB
#define CNT_OFF    721408u                       // 2*64K*4 = 512KB (adjacent to HIST for one zero)
#define RANK_OFF   1245696u                      // 2*64K*4 = 512KB
#define SEG_OFF    1769984u                      // 2*8192*8 = 128KB -> end 1901056

__global__ void k_zero(u32* p, int n) {
    int i = blockIdx.x * blockDim.x + threadIdx.x;
    if (i < n) p[i] = 0u;
}

__device__ __forceinline__ int score_bucket(float s) {
    int bk = (int)(s * 65536.0f);
    return bk < 0 ? 0 : (bk > 65535 ? 65535 : bk);
}

__global__ void k_hist(const float* __restrict__ cls, int* __restrict__ hist) {
    int b = blockIdx.y;
    int stride = gridDim.x * blockDim.x;
    for (int i = blockIdx.x * blockDim.x + threadIdx.x; i < NANCH; i += stride) {
        float s = cls[((size_t)b * NANCH + i) * 2 + 1];
        atomicAdd(&hist[b * NBUCK + score_bucket(s)], 1);
    }
}

// threshold bucket: largest T with count(bucket >= T) >= PRE_NMS
__global__ void k_thresh(const int* __restrict__ hist, int* __restrict__ meta) {
    __shared__ int chunk[256];
    __shared__ int suffix[256];
    int b = blockIdx.x, t = threadIdx.x;
    const int* h = hist + b * NBUCK;
    int s = 0;
    for (int c = 0; c < 256; ++c) s += h[t * 256 + c];
    chunk[t] = s;
    __syncthreads();
    if (t == 0) {
        int run = 0;
        for (int u = 255; u >= 0; --u) { suffix[u] = run; run += chunk[u]; }
    }
    __syncthreads();
    if (suffix[t] < PRE_NMS && suffix[t] + chunk[t] >= PRE_NMS) {
        int running = suffix[t];
        for (int c = 255; c >= 0; --c) {
            running += h[t * 256 + c];
            if (running >= PRE_NMS) { meta[b] = t * 256 + c; break; }
        }
    }
}

// rank_start[b][k] = # candidates in buckets strictly above k  (suffix-exclusive scan)
__global__ __launch_bounds__(1024) void k_offsets(const int* __restrict__ hist,
                                                  int* __restrict__ rank_start) {
    __shared__ int s[1024];
    int b = blockIdx.x, t = threadIdx.x;
    const int* h = hist + b * NBUCK;
    int base = t * 64;
    int csum = 0;
    for (int c = 0; c < 64; ++c) csum += h[base + c];
    s[t] = csum;
    __syncthreads();
    for (int off = 1; off < 1024; off <<= 1) {
        int v = (t + off < 1024) ? s[t + off] : 0;
        __syncthreads();
        s[t] += v;
        __syncthreads();
    }
    int excl = s[t] - csum;          // sum of chunks strictly above mine
    int acc = 0;
    int* rs = rank_start + b * NBUCK;
    for (int c = 63; c >= 0; --c) {
        rs[base + c] = excl + acc;
        acc += h[base + c];
    }
}

// scatter candidates >= threshold bucket into their bucket segment
__global__ void k_scatter(const float* __restrict__ cls, const int* __restrict__ meta,
                          const int* __restrict__ rank_start, int* __restrict__ cnt,
                          u64* __restrict__ seg) {
    int b = blockIdx.y;
    int thr = meta[b];
    int stride = gridDim.x * blockDim.x;
    for (int i = blockIdx.x * blockDim.x + threadIdx.x; i < NANCH; i += stride) {
        float s = cls[((size_t)b * NANCH + i) * 2 + 1];
        int bk = score_bucket(s);
        if (bk >= thr) {
            int pos = atomicAdd(&cnt[b * NBUCK + bk], 1);
            int slot = rank_start[b * NBUCK + bk] + pos;
            if (slot < SEG_CAP) {
                u32 sb = __float_as_uint(s);
                seg[b * SEG_CAP + slot] = ((u64)sb << 32) | (u32)(~(u32)i);
            }
        }
    }
}

// one thread per active bucket: in-place selection sort (descending) of its segment
__global__ void k_bsort(const int* __restrict__ meta, const int* __restrict__ rank_start,
                        const int* __restrict__ cnt, u64* __restrict__ seg) {
    int b = blockIdx.y;
    int bk = blockIdx.x * blockDim.x + threadIdx.x;
    if (bk >= NBUCK || bk < meta[b]) return;
    int c = cnt[b * NBUCK + bk];
    if (c < 2) return;
    int st = rank_start[b * NBUCK + bk];
    int en = st + c; if (en > SEG_CAP) en = SEG_CAP;
    u64* sg = seg + b * SEG_CAP;
    for (int i = st; i < en - 1; ++i) {
        u64 best = sg[i]; int bi = i;
        for (int j = i + 1; j < en; ++j) {
            u64 v = sg[j];
            if (v > best) { best = v; bi = j; }
        }
        if (bi != i) { sg[bi] = sg[i]; sg[i] = best; }
    }
}

// decode top-6000 rank-ordered boxes
__global__ void k_build(const u64* __restrict__ seg,
                        const float4* __restrict__ anchors, const float4* __restrict__ bbox,
                        float4* __restrict__ boxes) {
    #pragma clang fp contract(off)
    int g = blockIdx.x * blockDim.x + threadIdx.x;
    if (g >= BATCH * PRE_NMS) return;
    int b = g / PRE_NMS, r = g % PRE_NMS;
    u64 key = seg[b * SEG_CAP + r];
    u32 idx = ~(u32)(key & 0xffffffffull);
    float4 a = anchors[(size_t)b * NANCH + idx];
    float4 d = bbox[(size_t)b * NANCH + idx];
    float dy = d.x * 0.1f, dx = d.y * 0.1f, dh = d.z * 0.2f, dw = d.w * 0.2f;
    float h = a.z - a.x;
    float w = a.w - a.y;
    float cy = a.x + 0.5f * h + dy * h;
    float cx = a.y + 0.5f * w + dx * w;
    h = h * expf(dh);
    w = w * expf(dw);
    float y1 = cy - 0.5f * h;
    float x1 = cx - 0.5f * w;
    float y2 = y1 + h;
    float x2 = x1 + w;
    y1 = fminf(fmaxf(y1, 0.f), 1.f);
    x1 = fminf(fmaxf(x1, 0.f), 1.f);
    y2 = fminf(fmaxf(y2, 0.f), 1.f);
    x2 = fminf(fmaxf(x2, 0.f), 1.f);
    boxes[b * PRE_NMS + r] = make_float4(y1, x1, y2, x2);
}

// block-tiled mask: mask[((b*NT+T)*NT+W)*64 + lane], bit c = IoU(row box 64W+lane, col box 64T+c) > thr
// nz[(b*NT+T)*2 + (W>>6)] bit (W&63): any suppression bit in block (T, W), W > T only.
__global__ __launch_bounds__(256) void k_mask(const float4* __restrict__ boxes,
                                              u64* __restrict__ mask, u64* __restrict__ nz) {
    #pragma clang fp contract(off)
    __shared__ float4 tb[64];
    __shared__ float ta[64];
    int b = blockIdx.z;
    int T = blockIdx.y;
    int w = threadIdx.x >> 6, lane = threadIdx.x & 63;
    int W = blockIdx.x * 4 + w;
    if (threadIdx.x < 64) {
        int c = T * 64 + threadIdx.x;
        float4 v = (c < PRE_NMS) ? boxes[b * PRE_NMS + c] : make_float4(0.f, 0.f, 0.f, 0.f);
        tb[threadIdx.x] = v;
        ta[threadIdx.x] = (v.z - v.x) * (v.w - v.y);
    }
    __syncthreads();
    if (W < T || W >= NT) return;
    int j = W * 64 + lane;
    u64 word = 0;
    if (j < PRE_NMS) {
        float4 bj = boxes[b * PRE_NMS + j];
        float areaj = (bj.z - bj.x) * (bj.w - bj.y);
        for (int c = 0; c < 64; ++c) {
            float4 bi = tb[c];
            float ih = fminf(bi.z, bj.z) - fmaxf(bi.x, bj.x); ih = fmaxf(ih, 0.f);
            float iw = fminf(bi.w, bj.w) - fmaxf(bi.y, bj.y); iw = fmaxf(iw, 0.f);
            float inter = ih * iw;
            float iou = inter / (ta[c] + areaj - inter + 1e-8f);
            if (iou > NMS_THR) word |= (1ull << c);
        }
    }
    mask[(((size_t)b * NT + T) * NT + W) * 64 + lane] = word;
    if (W > T) {
        u64 any = __ballot(word != 0);
        if (lane == 0 && any)
            atomicOr((unsigned long long*)&nz[(b * NT + T) * 2 + (W >> 6)], 1ull << (W & 63));
    }
}

// single wave per batch; removed bitmask in LDS; sparse serial resolve + nz-driven propagate
__global__ __launch_bounds__(64) void k_scan(const u64* __restrict__ mask,
                                             const u64* __restrict__ nz,
                                             u64* __restrict__ keptw) {
    __shared__ u64 remAll[NT];
    int b = blockIdx.x, lane = threadIdx.x;
    for (int i = lane; i < NT; i += 64) remAll[i] = 0;
    __syncthreads();
    u64 himaskL = (lane == 63) ? 0ull : (~0ull << (lane + 1));
    size_t basebt = (size_t)b * NT;
    u64 m = mask[((basebt + 0) * NT + 0) * 64 + lane];
    for (int T = 0; T < NT; ++T) {
        u64 m_next = (T + 1 < NT) ? mask[((basebt + T + 1) * NT + (T + 1)) * 64 + lane] : 0ull;
        int limit = PRE_NMS - T * 64; if (limit > 64) limit = 64;
        u64 valid = (limit >= 64) ? ~0ull : ((1ull << limit) - 1ull);
        u64 rem = remAll[T];
        u64 pending = valid & ~rem;
        u64 ib = __ballot((m & himaskL) != 0ull);
        u64 todo = pending & ib;
        while (todo) {
            int l0 = __ffsll((unsigned long long)todo) - 1;
            todo &= todo - 1;
            if ((rem >> l0) & 1ull) continue;
            u64 sup = __shfl(m, l0);
            sup &= (l0 == 63) ? 0ull : (~0ull << (l0 + 1));
            rem |= sup;
            todo &= ~sup;
        }
        u64 kept = valid & ~rem;
        if (lane == 0) keptw[b * 96 + T] = kept;
        // propagate to nonzero future blocks only
        u64 nz0 = nz[(basebt + T) * 2 + 0];
        u64 nz1 = nz[(basebt + T) * 2 + 1];
        if (T < 64) {
            nz0 &= (T == 63) ? 0ull : (~0ull << (T + 1));
        } else {
            nz0 = 0ull;
            nz1 &= (~0ull << (T - 63));
        }
        bool updated = false;
        while (nz0 | nz1) {
            int W;
            if (nz0) { W = __ffsll((unsigned long long)nz0) - 1; nz0 &= nz0 - 1; }
            else     { W = 64 + __ffsll((unsigned long long)nz1) - 1; nz1 &= nz1 - 1; }
            u64 mw = mask[((basebt + T) * NT + W) * 64 + lane];
            u64 ra = __ballot((mw & kept) != 0ull);
            if (ra) { if (lane == 0) remAll[W] |= ra; updated = true; }
        }
        if (updated) __syncthreads();
        m = m_next;
    }
}

__global__ __launch_bounds__(1024) void k_output(
        const float4* __restrict__ boxes, const u64* __restrict__ keptw,
        float* __restrict__ out) {
    __shared__ int wp[NT + 1];
    int b = blockIdx.x, t = threadIdx.x;
    for (int i = t; i < PROP * 4; i += 1024) out[b * PROP * 4 + i] = 0.f;
    if (t < NT) wp[t + 1] = __popcll(keptw[b * 96 + t]);
    if (t == 0) wp[0] = 0;
    __syncthreads();
    if (t == 0) { for (int i = 1; i <= NT; ++i) wp[i] += wp[i - 1]; }
    __syncthreads();
    float4* out4 = (float4*)(out + b * PROP * 4);
    for (int j = t; j < PRE_NMS; j += 1024) {
        u64 w = keptw[b * 96 + (j >> 6)];
        int bit = j & 63;
        if ((w >> bit) & 1ull) {
            int rank = wp[j >> 6] + __popcll(w & ((1ull << bit) - 1ull));
            if (rank < PROP) out4[rank] = boxes[b * PRE_NMS + j];
        }
    }
}

extern "C" void kernel_launch(void* const* d_in, const int* in_sizes, int n_in,
                              void* d_out, int out_size, void* d_ws, size_t ws_size,
                              hipStream_t stream) {
    const float*  cls     = (const float*)d_in[0];
    const float4* bbox    = (const float4*)d_in[1];
    const float4* anchors = (const float4*)d_in[2];
    float* out = (float*)d_out;
    char* w = (char*)d_ws;
    int*    meta  = (int*)(w + META_OFF);      // [0..1] = threshold bucket per batch
    float4* boxes = (float4*)(w + BOXES_OFF);
    u64*    keptw = (u64*)(w + KEPTW_OFF);
    u64*    nz    = (u64*)(w + NZ_OFF);
    u64*    mask  = (u64*)(w + MASK_OFF);
    int*    hist  = (int*)(w + HIST_OFF);      // overlaps mask (dead before k_mask)
    int*    cnt   = (int*)(w + CNT_OFF);       // overlaps mask
    int*    rank  = (int*)(w + RANK_OFF);      // overlaps mask
    u64*    seg   = (u64*)(w + SEG_OFF);       // overlaps mask

    // zero hist+cnt (adjacent, 1MB) and keptw+nz (4544B)
    k_zero<<<dim3((2 * BATCH * NBUCK + 255) / 256), 256, 0, stream>>>((u32*)hist, 2 * BATCH * NBUCK);
    k_zero<<<dim3(((1536 + 3008) / 4 + 255) / 256), 256, 0, stream>>>((u32*)keptw, (1536 + 3008) / 4);
    k_hist<<<dim3(256, BATCH), 256, 0, stream>>>(cls, hist);
    k_thresh<<<dim3(BATCH), 256, 0, stream>>>(hist, meta);
    k_offsets<<<dim3(BATCH), 1024, 0, stream>>>(hist, rank);
    k_scatter<<<dim3(256, BATCH), 256, 0, stream>>>(cls, meta, rank, cnt, seg);
    k_bsort<<<dim3(NBUCK / 256, BATCH), 256, 0, stream>>>(meta, rank, cnt, seg);
    k_build<<<dim3((BATCH * PRE_NMS + 255) / 256), 256, 0, stream>>>(seg, anchors, bbox, boxes);
    k_mask<<<dim3(24, NT, BATCH), 256, 0, stream>>>(boxes, mask, nz);
    k_scan<<<dim3(BATCH), 64, 0, stream>>>(mask, nz, keptw);
    k_output<<<dim3(BATCH), 1024, 0, stream>>>(boxes, keptw, out);
}

// Round 4
// 202.499 us; speedup vs baseline: 6.0386x; 1.6885x over previous
//
#include <hip/hip_runtime.h>
#include <cstdint>

#define BATCH   2
#define NANCH   261888
#define PRE_NMS 6000
#define PROP    1000
#define NBUCK   65536
#define SEG_CAP 8192
#define ECAP    65536
#define NT      94          // ceil(6000/64)
#define NMS_THR 0.7f

typedef unsigned long long u64;
typedef unsigned int u32;

// ---- workspace layout (bytes), no overlap needed (~2.4MB total) ----
#define META_OFF   0u                            // int[8]: [0..1]=thr bucket, [4..5]=edge count
#define BOXES_OFF  256u                          // 2*6000*16 = 192000 -> 192256
#define KEPTW_OFF  192256u                       // 2*96*8 = 1536     -> 193792
#define EDGES_OFF  193792u                       // 2*65536*4 = 524288-> 718080
#define HIST_OFF   718080u                       // 512KB -> 1242368
#define CNT_OFF    1242368u                      // 512KB -> 1766656  (adjacent to HIST: one zero)
#define RANK_OFF   1766656u                      // 512KB -> 2290944
#define SEG_OFF    2290944u                      // 128KB -> 2422016

__global__ void k_zero(u32* p, int n) {
    int i = blockIdx.x * blockDim.x + threadIdx.x;
    if (i < n) p[i] = 0u;
}

__device__ __forceinline__ int score_bucket(float s) {
    int bk = (int)(s * 65536.0f);
    return bk < 0 ? 0 : (bk > 65535 ? 65535 : bk);
}

__global__ void k_hist(const float* __restrict__ cls, int* __restrict__ hist,
                       int* __restrict__ meta) {
    int b = blockIdx.y;
    if (blockIdx.x == 0 && threadIdx.x == 0) meta[4 + b] = 0;   // edge counter
    int stride = gridDim.x * blockDim.x;
    for (int i = blockIdx.x * blockDim.x + threadIdx.x; i < NANCH; i += stride) {
        float s = cls[((size_t)b * NANCH + i) * 2 + 1];
        atomicAdd(&hist[b * NBUCK + score_bucket(s)], 1);
    }
}

// suffix-exclusive scan of 64K histogram -> rank_start; also finds threshold bucket
__global__ __launch_bounds__(1024) void k_offsets(const int* __restrict__ hist,
                                                  int* __restrict__ rank_start,
                                                  int* __restrict__ meta) {
    __shared__ int s[1024];
    int b = blockIdx.x, t = threadIdx.x;
    const int* h = hist + b * NBUCK;
    int base = t * 64;
    int hv[64];
    int csum = 0;
    for (int c = 0; c < 64; ++c) { hv[c] = h[base + c]; csum += hv[c]; }
    s[t] = csum;
    __syncthreads();
    for (int off = 1; off < 1024; off <<= 1) {
        int v = (t + off < 1024) ? s[t + off] : 0;
        __syncthreads();
        s[t] += v;
        __syncthreads();
    }
    int excl = s[t] - csum;          // candidates in buckets strictly above my chunk
    int acc = 0;
    int* rs = rank_start + b * NBUCK;
    for (int c = 63; c >= 0; --c) {
        int r = excl + acc;          // rank_start for bucket base+c
        rs[base + c] = r;
        acc += hv[c];
        if (r < PRE_NMS && r + hv[c] >= PRE_NMS) meta[b] = base + c;  // unique crossing bucket
    }
}

// scatter candidates >= threshold bucket into their bucket segment (exact global rank)
__global__ void k_scatter(const float* __restrict__ cls, const int* __restrict__ meta,
                          const int* __restrict__ rank_start, int* __restrict__ cnt,
                          u64* __restrict__ seg) {
    int b = blockIdx.y;
    int thr = meta[b];
    int stride = gridDim.x * blockDim.x;
    for (int i = blockIdx.x * blockDim.x + threadIdx.x; i < NANCH; i += stride) {
        float s = cls[((size_t)b * NANCH + i) * 2 + 1];
        int bk = score_bucket(s);
        if (bk >= thr) {
            int pos = atomicAdd(&cnt[b * NBUCK + bk], 1);
            int slot = rank_start[b * NBUCK + bk] + pos;
            if (slot < SEG_CAP) {
                u32 sb = __float_as_uint(s);
                seg[b * SEG_CAP + slot] = ((u64)sb << 32) | (u32)(~(u32)i);
            }
        }
    }
}

// one thread per active bucket: in-place selection sort (descending) of its tiny segment
__global__ void k_bsort(const int* __restrict__ meta, const int* __restrict__ rank_start,
                        const int* __restrict__ cnt, u64* __restrict__ seg) {
    int b = blockIdx.y;
    int bk = blockIdx.x * blockDim.x + threadIdx.x;
    if (bk >= NBUCK || bk < meta[b]) return;
    int c = cnt[b * NBUCK + bk];
    if (c < 2) return;
    int st = rank_start[b * NBUCK + bk];
    int en = st + c; if (en > SEG_CAP) en = SEG_CAP;
    u64* sg = seg + b * SEG_CAP;
    for (int i = st; i < en - 1; ++i) {
        u64 best = sg[i]; int bi = i;
        for (int j = i + 1; j < en; ++j) {
            u64 v = sg[j];
            if (v > best) { best = v; bi = j; }
        }
        if (bi != i) { sg[bi] = sg[i]; sg[i] = best; }
    }
}

// decode top-6000 rank-ordered boxes (exact reference math, contract off)
__global__ void k_build(const u64* __restrict__ seg,
                        const float4* __restrict__ anchors, const float4* __restrict__ bbox,
                        float4* __restrict__ boxes) {
    #pragma clang fp contract(off)
    int g = blockIdx.x * blockDim.x + threadIdx.x;
    if (g >= BATCH * PRE_NMS) return;
    int b = g / PRE_NMS, r = g % PRE_NMS;
    u64 key = seg[b * SEG_CAP + r];
    u32 idx = ~(u32)(key & 0xffffffffull);
    float4 a = anchors[(size_t)b * NANCH + idx];
    float4 d = bbox[(size_t)b * NANCH + idx];
    float dy = d.x * 0.1f, dx = d.y * 0.1f, dh = d.z * 0.2f, dw = d.w * 0.2f;
    float h = a.z - a.x;
    float w = a.w - a.y;
    float cy = a.x + 0.5f * h + dy * h;
    float cx = a.y + 0.5f * w + dx * w;
    h = h * expf(dh);
    w = w * expf(dw);
    float y1 = cy - 0.5f * h;
    float x1 = cx - 0.5f * w;
    float y2 = y1 + h;
    float x2 = x1 + w;
    y1 = fminf(fmaxf(y1, 0.f), 1.f);
    x1 = fminf(fmaxf(x1, 0.f), 1.f);
    y2 = fminf(fmaxf(y2, 0.f), 1.f);
    x2 = fminf(fmaxf(x2, 0.f), 1.f);
    boxes[b * PRE_NMS + r] = make_float4(y1, x1, y2, x2);
}

// IoU > thr pairs (i<j) appended as packed edges (j<<13)|i
__global__ __launch_bounds__(256) void k_mask(const float4* __restrict__ boxes,
                                              u32* __restrict__ edges, int* __restrict__ ecnt) {
    #pragma clang fp contract(off)
    __shared__ float4 tb[64];
    __shared__ float ta[64];
    int b = blockIdx.z;
    int T = blockIdx.y;
    int w = threadIdx.x >> 6, lane = threadIdx.x & 63;
    int W = blockIdx.x * 4 + w;
    if (threadIdx.x < 64) {
        int c = T * 64 + threadIdx.x;
        float4 v = (c < PRE_NMS) ? boxes[b * PRE_NMS + c] : make_float4(0.f, 0.f, 0.f, 0.f);
        tb[threadIdx.x] = v;
        ta[threadIdx.x] = (v.z - v.x) * (v.w - v.y);
    }
    __syncthreads();
    if (W < T || W >= NT) return;
    int j = W * 64 + lane;
    u64 word = 0;
    if (j < PRE_NMS) {
        float4 bj = boxes[b * PRE_NMS + j];
        float areaj = (bj.z - bj.x) * (bj.w - bj.y);
        for (int c = 0; c < 64; ++c) {
            float4 bi = tb[c];
            float ih = fminf(bi.z, bj.z) - fmaxf(bi.x, bj.x); ih = fmaxf(ih, 0.f);
            float iw = fminf(bi.w, bj.w) - fmaxf(bi.y, bj.y); iw = fmaxf(iw, 0.f);
            float inter = ih * iw;
            float iou = inter / (ta[c] + areaj - inter + 1e-8f);
            if (iou > NMS_THR) word |= (1ull << c);
        }
    }
    if (W == T) word &= (lane ? ((1ull << lane) - 1ull) : 0ull);   // keep i<j only
    while (word) {
        int c = __ffsll((unsigned long long)word) - 1;
        word &= word - 1;
        int i = T * 64 + c;
        int pos = atomicAdd(&ecnt[b], 1);
        if (pos < ECAP) edges[b * ECAP + pos] = ((u32)j << 13) | (u32)i;
    }
}

// exact greedy NMS on the sparse edge list; monotone fixed point, all in LDS
__global__ __launch_bounds__(256) void k_resolve(const u32* __restrict__ edges,
                                                 const int* __restrict__ ecnt,
                                                 u64* __restrict__ keptw) {
    __shared__ unsigned char st[6016];   // 0=unknown 1=kept(final) 2=removed(final)
    __shared__ u32 cnt[6016];
    __shared__ int changed;
    int b = blockIdx.x, t = threadIdx.x;
    int E = ecnt[b]; if (E > ECAP) E = ECAP;
    const u32* eb = edges + (size_t)b * ECAP;
    for (int j = t; j < 6016; j += 256) st[j] = 1;
    __syncthreads();
    for (int k = t; k < E; k += 256) st[eb[k] >> 13] = 0;   // has suppressor -> unknown
    __syncthreads();
    while (true) {
        if (t == 0) changed = 0;
        __syncthreads();
        // removal: final-kept i suppresses unknown j (1 is never demoted -> race-safe)
        for (int k = t; k < E; k += 256) {
            u32 e = eb[k]; int i = e & 8191, j = e >> 13;
            if (st[i] == 1 && st[j] == 0) { st[j] = 2; changed = 1; }
        }
        __syncthreads();
        // promotion: unknown j with all suppressors removed -> kept
        for (int j = t; j < 6016; j += 256) cnt[j] = 0;
        __syncthreads();
        for (int k = t; k < E; k += 256) {
            u32 e = eb[k]; int i = e & 8191, j = e >> 13;
            if (st[i] != 2) atomicAdd(&cnt[j], 1u);
        }
        __syncthreads();
        for (int j = t; j < 6016; j += 256) {
            if (st[j] == 0 && cnt[j] == 0) { st[j] = 1; changed = 1; }
        }
        __syncthreads();
        if (!changed) break;
    }
    for (int w = t; w < NT; w += 256) {
        int base = w * 64;
        int lim = PRE_NMS - base; if (lim > 64) lim = 64;
        u64 bits = 0;
        for (int l = 0; l < lim; ++l) if (st[base + l] == 1) bits |= (1ull << l);
        keptw[b * 96 + w] = bits;
    }
}

__global__ __launch_bounds__(1024) void k_output(
        const float4* __restrict__ boxes, const u64* __restrict__ keptw,
        float* __restrict__ out) {
    __shared__ int wp[NT + 1];
    int b = blockIdx.x, t = threadIdx.x;
    for (int i = t; i < PROP * 4; i += 1024) out[b * PROP * 4 + i] = 0.f;
    if (t < NT) wp[t + 1] = __popcll(keptw[b * 96 + t]);
    if (t == 0) wp[0] = 0;
    __syncthreads();
    if (t == 0) { for (int i = 1; i <= NT; ++i) wp[i] += wp[i - 1]; }
    __syncthreads();
    float4* out4 = (float4*)(out + b * PROP * 4);
    for (int j = t; j < PRE_NMS; j += 1024) {
        u64 w = keptw[b * 96 + (j >> 6)];
        int bit = j & 63;
        if ((w >> bit) & 1ull) {
            int rank = wp[j >> 6] + __popcll(w & ((1ull << bit) - 1ull));
            if (rank < PROP) out4[rank] = boxes[b * PRE_NMS + j];
        }
    }
}

extern "C" void kernel_launch(void* const* d_in, const int* in_sizes, int n_in,
                              void* d_out, int out_size, void* d_ws, size_t ws_size,
                              hipStream_t stream) {
    const float*  cls     = (const float*)d_in[0];
    const float4* bbox    = (const float4*)d_in[1];
    const float4* anchors = (const float4*)d_in[2];
    float* out = (float*)d_out;
    char* w = (char*)d_ws;
    int*    meta  = (int*)(w + META_OFF);
    float4* boxes = (float4*)(w + BOXES_OFF);
    u64*    keptw = (u64*)(w + KEPTW_OFF);
    u32*    edges = (u32*)(w + EDGES_OFF);
    int*    hist  = (int*)(w + HIST_OFF);
    int*    cnt   = (int*)(w + CNT_OFF);
    int*    rank  = (int*)(w + RANK_OFF);
    u64*    seg   = (u64*)(w + SEG_OFF);

    k_zero<<<dim3((2 * BATCH * NBUCK + 255) / 256), 256, 0, stream>>>((u32*)hist, 2 * BATCH * NBUCK);
    k_hist<<<dim3(256, BATCH), 256, 0, stream>>>(cls, hist, meta);
    k_offsets<<<dim3(BATCH), 1024, 0, stream>>>(hist, rank, meta);
    k_scatter<<<dim3(256, BATCH), 256, 0, stream>>>(cls, meta, rank, cnt, seg);
    k_bsort<<<dim3(NBUCK / 256, BATCH), 256, 0, stream>>>(meta, rank, cnt, seg);
    k_build<<<dim3((BATCH * PRE_NMS + 255) / 256), 256, 0, stream>>>(seg, anchors, bbox, boxes);
    k_mask<<<dim3(24, NT, BATCH), 256, 0, stream>>>(boxes, edges, meta + 4);
    k_resolve<<<dim3(BATCH), 256, 0, stream>>>(edges, meta + 4, keptw);
    k_output<<<dim3(BATCH), 1024, 0, stream>>>(boxes, keptw, out);
}

// Round 5
// 156.073 us; speedup vs baseline: 7.8349x; 1.2975x over previous
//
#include <hip/hip_runtime.h>
#include <cstdint>

#define BATCH   2
#define NANCH   261888
#define PRE_NMS 6000
#define PROP    1000
#define NBUCK   65536
#define SEG_CAP 8192
#define ECAP    65536
#define NT      94          // ceil(6000/64)
#define NMS_THR 0.7f

typedef unsigned long long u64;
typedef unsigned int u32;

// ---- workspace layout (bytes) ----
#define META_OFF   0u                            // int[8]: [0..1]=thr bucket, [4..5]=edge count
#define BOXES_OFF  256u                          // 2*6000*16 = 192000 -> 192256
#define KEPTW_OFF  192256u                       // 2*96*8 = 1536     -> 193792
#define EDGES_OFF  193792u                       // 2*65536*4 = 524288-> 718080
#define HIST_OFF   718080u                       // 512KB -> 1242368
#define CNT_OFF    1242368u                      // 512KB -> 1766656  (adjacent to HIST: one zero)
#define RANK_OFF   1766656u                      // 512KB -> 2290944
#define SEG_OFF    2290944u                      // 128KB -> 2422016
#define CHS_OFF    2422016u                      // 2*256*4 = 2KB -> 2424064

__global__ void k_zero(u32* p, int n) {
    int i = blockIdx.x * blockDim.x + threadIdx.x;
    if (i < n) p[i] = 0u;
}

__device__ __forceinline__ int score_bucket(float s) {
    int bk = (int)(s * 65536.0f);
    return bk < 0 ? 0 : (bk > 65535 ? 65535 : bk);
}

__global__ void k_hist(const float* __restrict__ cls, int* __restrict__ hist,
                       int* __restrict__ meta) {
    int b = blockIdx.y;
    if (blockIdx.x == 0 && threadIdx.x == 0) meta[4 + b] = 0;   // edge counter
    int stride = gridDim.x * blockDim.x;
    for (int i = blockIdx.x * blockDim.x + threadIdx.x; i < NANCH; i += stride) {
        float s = cls[((size_t)b * NANCH + i) * 2 + 1];
        atomicAdd(&hist[b * NBUCK + score_bucket(s)], 1);
    }
}

// per-256-bucket chunk sums: grid (256, BATCH), coalesced
__global__ __launch_bounds__(256) void k_chunks(const int* __restrict__ hist,
                                                int* __restrict__ chunksum) {
    __shared__ int s[256];
    int b = blockIdx.y, ch = blockIdx.x, t = threadIdx.x;
    s[t] = hist[b * NBUCK + ch * 256 + t];
    __syncthreads();
    for (int off = 128; off > 0; off >>= 1) {
        if (t < off) s[t] += s[t + off];
        __syncthreads();
    }
    if (t == 0) chunksum[b * 256 + ch] = s[0];
}

// per-bucket rank_start (count strictly above) + threshold bucket; grid (256, BATCH)
__global__ __launch_bounds__(256) void k_ranks(const int* __restrict__ hist,
                                               const int* __restrict__ chunksum,
                                               int* __restrict__ rank_start,
                                               int* __restrict__ meta) {
    __shared__ int sc[256];
    __shared__ int sh[256];
    int b = blockIdx.y, ch = blockIdx.x, t = threadIdx.x;
    sc[t] = chunksum[b * 256 + t];
    __syncthreads();
    for (int off = 1; off < 256; off <<= 1) {        // sc[t] = sum_{u>=t} chunksum[u]
        int add = (t + off < 256) ? sc[t + off] : 0;
        __syncthreads();
        sc[t] += add;
        __syncthreads();
    }
    int hv = hist[b * NBUCK + ch * 256 + t];
    sh[t] = hv;
    __syncthreads();
    for (int off = 1; off < 256; off <<= 1) {        // sh[t] = within-chunk sum_{u>=t}
        int add = (t + off < 256) ? sh[t + off] : 0;
        __syncthreads();
        sh[t] += add;
        __syncthreads();
    }
    int excl_ch = (ch + 1 < 256) ? sc[ch + 1] : 0;   // chunks strictly above mine
    int r = excl_ch + sh[t] - hv;                    // buckets strictly above this one
    rank_start[b * NBUCK + ch * 256 + t] = r;
    if (r < PRE_NMS && r + hv >= PRE_NMS) meta[b] = ch * 256 + t;  // unique crossing bucket
}

// scatter candidates >= threshold bucket into their bucket segment (exact global rank)
__global__ void k_scatter(const float* __restrict__ cls, const int* __restrict__ meta,
                          const int* __restrict__ rank_start, int* __restrict__ cnt,
                          u64* __restrict__ seg) {
    int b = blockIdx.y;
    int thr = meta[b];
    int stride = gridDim.x * blockDim.x;
    for (int i = blockIdx.x * blockDim.x + threadIdx.x; i < NANCH; i += stride) {
        float s = cls[((size_t)b * NANCH + i) * 2 + 1];
        int bk = score_bucket(s);
        if (bk >= thr) {
            int pos = atomicAdd(&cnt[b * NBUCK + bk], 1);
            int slot = rank_start[b * NBUCK + bk] + pos;
            if (slot < SEG_CAP) {
                u32 sb = __float_as_uint(s);
                seg[b * SEG_CAP + slot] = ((u64)sb << 32) | (u32)(~(u32)i);
            }
        }
    }
}

// one thread per active bucket: in-place selection sort (descending) of its tiny segment
__global__ void k_bsort(const int* __restrict__ meta, const int* __restrict__ rank_start,
                        const int* __restrict__ cnt, u64* __restrict__ seg) {
    int b = blockIdx.y;
    int bk = blockIdx.x * blockDim.x + threadIdx.x;
    if (bk >= NBUCK || bk < meta[b]) return;
    int c = cnt[b * NBUCK + bk];
    if (c < 2) return;
    int st = rank_start[b * NBUCK + bk];
    int en = st + c; if (en > SEG_CAP) en = SEG_CAP;
    u64* sg = seg + b * SEG_CAP;
    for (int i = st; i < en - 1; ++i) {
        u64 best = sg[i]; int bi = i;
        for (int j = i + 1; j < en; ++j) {
            u64 v = sg[j];
            if (v > best) { best = v; bi = j; }
        }
        if (bi != i) { sg[bi] = sg[i]; sg[i] = best; }
    }
}

// decode top-6000 rank-ordered boxes (exact reference math, contract off)
__global__ void k_build(const u64* __restrict__ seg,
                        const float4* __restrict__ anchors, const float4* __restrict__ bbox,
                        float4* __restrict__ boxes) {
    #pragma clang fp contract(off)
    int g = blockIdx.x * blockDim.x + threadIdx.x;
    if (g >= BATCH * PRE_NMS) return;
    int b = g / PRE_NMS, r = g % PRE_NMS;
    u64 key = seg[b * SEG_CAP + r];
    u32 idx = ~(u32)(key & 0xffffffffull);
    float4 a = anchors[(size_t)b * NANCH + idx];
    float4 d = bbox[(size_t)b * NANCH + idx];
    float dy = d.x * 0.1f, dx = d.y * 0.1f, dh = d.z * 0.2f, dw = d.w * 0.2f;
    float h = a.z - a.x;
    float w = a.w - a.y;
    float cy = a.x + 0.5f * h + dy * h;
    float cx = a.y + 0.5f * w + dx * w;
    h = h * expf(dh);
    w = w * expf(dw);
    float y1 = cy - 0.5f * h;
    float x1 = cx - 0.5f * w;
    float y2 = y1 + h;
    float x2 = x1 + w;
    y1 = fminf(fmaxf(y1, 0.f), 1.f);
    x1 = fminf(fmaxf(x1, 0.f), 1.f);
    y2 = fminf(fmaxf(y2, 0.f), 1.f);
    x2 = fminf(fmaxf(x2, 0.f), 1.f);
    boxes[b * PRE_NMS + r] = make_float4(y1, x1, y2, x2);
}

// IoU > thr pairs (i<j) appended as packed edges (j<<13)|i.
// Division-skip: iou>0.7 requires inter > 0.7*max(areas); filter at 0.69 is
// conservatively safe (>1% margin vs ~1e-6 fp rounding), exact path unchanged.
__global__ __launch_bounds__(256) void k_mask(const float4* __restrict__ boxes,
                                              u32* __restrict__ edges, int* __restrict__ ecnt) {
    #pragma clang fp contract(off)
    __shared__ float4 tb[64];
    __shared__ float ta[64];
    int b = blockIdx.z;
    int T = blockIdx.y;
    if (blockIdx.x * 4 + 3 < T) return;          // fully-dead lower-triangle block
    int w = threadIdx.x >> 6, lane = threadIdx.x & 63;
    int W = blockIdx.x * 4 + w;
    if (threadIdx.x < 64) {
        int c = T * 64 + threadIdx.x;
        float4 v = (c < PRE_NMS) ? boxes[b * PRE_NMS + c] : make_float4(0.f, 0.f, 0.f, 0.f);
        tb[threadIdx.x] = v;
        ta[threadIdx.x] = (v.z - v.x) * (v.w - v.y);
    }
    __syncthreads();
    if (W < T || W >= NT) return;
    int j = W * 64 + lane;
    u64 word = 0;
    if (j < PRE_NMS) {
        float4 bj = boxes[b * PRE_NMS + j];
        float areaj = (bj.z - bj.x) * (bj.w - bj.y);
        for (int c = 0; c < 64; ++c) {
            float4 bi = tb[c];
            float ih = fminf(bi.z, bj.z) - fmaxf(bi.x, bj.x); ih = fmaxf(ih, 0.f);
            float iw = fminf(bi.w, bj.w) - fmaxf(bi.y, bj.y); iw = fmaxf(iw, 0.f);
            float inter = ih * iw;
            if (inter > 0.69f * fmaxf(ta[c], areaj)) {
                float iou = inter / (ta[c] + areaj - inter + 1e-8f);   // exact reference order
                if (iou > NMS_THR) word |= (1ull << c);
            }
        }
    }
    if (W == T) word &= (lane ? ((1ull << lane) - 1ull) : 0ull);   // keep i<j only
    while (word) {
        int c = __ffsll((unsigned long long)word) - 1;
        word &= word - 1;
        int i = T * 64 + c;
        int pos = atomicAdd(&ecnt[b], 1);
        if (pos < ECAP) edges[b * ECAP + pos] = ((u32)j << 13) | (u32)i;
    }
}

// exact greedy NMS on the sparse edge list; monotone fixed point, all in LDS
__global__ __launch_bounds__(256) void k_resolve(const u32* __restrict__ edges,
                                                 const int* __restrict__ ecnt,
                                                 u64* __restrict__ keptw) {
    __shared__ unsigned char st[6016];   // 0=unknown 1=kept(final) 2=removed(final)
    __shared__ u32 cnt[6016];
    __shared__ int changed;
    int b = blockIdx.x, t = threadIdx.x;
    int E = ecnt[b]; if (E > ECAP) E = ECAP;
    const u32* eb = edges + (size_t)b * ECAP;
    for (int j = t; j < 6016; j += 256) st[j] = 1;
    __syncthreads();
    for (int k = t; k < E; k += 256) st[eb[k] >> 13] = 0;   // has suppressor -> unknown
    __syncthreads();
    while (true) {
        if (t == 0) changed = 0;
        __syncthreads();
        for (int k = t; k < E; k += 256) {
            u32 e = eb[k]; int i = e & 8191, j = e >> 13;
            if (st[i] == 1 && st[j] == 0) { st[j] = 2; changed = 1; }
        }
        __syncthreads();
        for (int j = t; j < 6016; j += 256) cnt[j] = 0;
        __syncthreads();
        for (int k = t; k < E; k += 256) {
            u32 e = eb[k]; int i = e & 8191, j = e >> 13;
            if (st[i] != 2) atomicAdd(&cnt[j], 1u);
        }
        __syncthreads();
        for (int j = t; j < 6016; j += 256) {
            if (st[j] == 0 && cnt[j] == 0) { st[j] = 1; changed = 1; }
        }
        __syncthreads();
        if (!changed) break;
    }
    for (int w = t; w < NT; w += 256) {
        int base = w * 64;
        int lim = PRE_NMS - base; if (lim > 64) lim = 64;
        u64 bits = 0;
        for (int l = 0; l < lim; ++l) if (st[base + l] == 1) bits |= (1ull << l);
        keptw[b * 96 + w] = bits;
    }
}

__global__ __launch_bounds__(1024) void k_output(
        const float4* __restrict__ boxes, const u64* __restrict__ keptw,
        float* __restrict__ out) {
    __shared__ int wp[NT + 1];
    int b = blockIdx.x, t = threadIdx.x;
    for (int i = t; i < PROP * 4; i += 1024) out[b * PROP * 4 + i] = 0.f;
    if (t < NT) wp[t + 1] = __popcll(keptw[b * 96 + t]);
    if (t == 0) wp[0] = 0;
    __syncthreads();
    if (t == 0) { for (int i = 1; i <= NT; ++i) wp[i] += wp[i - 1]; }
    __syncthreads();
    float4* out4 = (float4*)(out + b * PROP * 4);
    for (int j = t; j < PRE_NMS; j += 1024) {
        u64 w = keptw[b * 96 + (j >> 6)];
        int bit = j & 63;
        if ((w >> bit) & 1ull) {
            int rank = wp[j >> 6] + __popcll(w & ((1ull << bit) - 1ull));
            if (rank < PROP) out4[rank] = boxes[b * PRE_NMS + j];
        }
    }
}

extern "C" void kernel_launch(void* const* d_in, const int* in_sizes, int n_in,
                              void* d_out, int out_size, void* d_ws, size_t ws_size,
                              hipStream_t stream) {
    const float*  cls     = (const float*)d_in[0];
    const float4* bbox    = (const float4*)d_in[1];
    const float4* anchors = (const float4*)d_in[2];
    float* out = (float*)d_out;
    char* w = (char*)d_ws;
    int*    meta   = (int*)(w + META_OFF);
    float4* boxes  = (float4*)(w + BOXES_OFF);
    u64*    keptw  = (u64*)(w + KEPTW_OFF);
    u32*    edges  = (u32*)(w + EDGES_OFF);
    int*    hist   = (int*)(w + HIST_OFF);
    int*    cnt    = (int*)(w + CNT_OFF);
    int*    rank   = (int*)(w + RANK_OFF);
    u64*    seg    = (u64*)(w + SEG_OFF);
    int*    chsum  = (int*)(w + CHS_OFF);

    k_zero<<<dim3((2 * BATCH * NBUCK + 255) / 256), 256, 0, stream>>>((u32*)hist, 2 * BATCH * NBUCK);
    k_hist<<<dim3(256, BATCH), 256, 0, stream>>>(cls, hist, meta);
    k_chunks<<<dim3(256, BATCH), 256, 0, stream>>>(hist, chsum);
    k_ranks<<<dim3(256, BATCH), 256, 0, stream>>>(hist, chsum, rank, meta);
    k_scatter<<<dim3(256, BATCH), 256, 0, stream>>>(cls, meta, rank, cnt, seg);
    k_bsort<<<dim3(NBUCK / 256, BATCH), 256, 0, stream>>>(meta, rank, cnt, seg);
    k_build<<<dim3((BATCH * PRE_NMS + 255) / 256), 256, 0, stream>>>(seg, anchors, bbox, boxes);
    k_mask<<<dim3(24, NT, BATCH), 256, 0, stream>>>(boxes, edges, meta + 4);
    k_resolve<<<dim3(BATCH), 256, 0, stream>>>(edges, meta + 4, keptw);
    k_output<<<dim3(BATCH), 1024, 0, stream>>>(boxes, keptw, out);
}